// Round 1
// baseline (201.812 us; speedup 1.0000x reference)
//
#include <hip/hip_runtime.h>
#include <math.h>

namespace {

constexpr int CIN  = 64;
constexpr int COUT = 128;
constexpr int LEN  = 4096;
constexpr int NT   = 512;
constexpr float INV_SQRT2 = 0.70710678118654752440f;

// Fast exact-enough GELU (tanh form as t*e/(e+1)). Max abs err ~1e-3 vs
// erf-exact; measured end-to-end absmax 0.0156 vs 0.0753 threshold.
__device__ __forceinline__ float gelu_fast(float t) {
    float t3 = t * t * t;
    float y  = 1.5957691216057308f * fmaf(0.044715f, t3, t);
    float e  = __expf(y);
    float d  = __builtin_amdgcn_rcpf(e + 1.0f);
    return t - t * d;   // t*e/(e+1); correct limits at +/-inf
}

// One block per (n, ic), producing output channels oc=2ic, 2ic+1.
// Restructured vs previous version: x is NOT staged through LDS. Each thread
// loads 4 overlapping (16B-aligned) float4s covering x[8t-4 .. 8t+11], which
// deinterleave to exactly the xe/xo halo window it needs (E[j]=xe[4t+j-2],
// O[j]=xo[4t+j-2]). Neighbor overlap is served by L1/L2, HBM fetch unchanged.
// Both channels' stage A run in one pass into dedicated per-channel coeff
// arrays, so the block needs exactly ONE __syncthreads (was 4).
// Coeff layout (zero-padded halos): sL[p] = xL0[p-4], writes p=4..2051,
// zeros at 0..3 and 2052..2055. Same for sH. All LDS ops are b128 at
// lane-stride 16B (conflict-free).
__global__ __launch_bounds__(NT, 4) void fused_wavelet_kernel(
    const float* __restrict__ x,
    const float* __restrict__ w1,
    const float* __restrict__ g1,
    const float* __restrict__ b1,
    const float* __restrict__ m1,
    const float* __restrict__ v1,
    const float* __restrict__ w2L,
    const float* __restrict__ w2H,
    const float* __restrict__ wskip,
    float* __restrict__ out)
{
    __shared__ float s0L[2056];
    __shared__ float s0H[2056];
    __shared__ float s1L[2056];
    __shared__ float s1H[2056];
    // 4*2056*4 = 32896 B (same LDS footprint as previous version)

    const int tid = threadIdx.x;
    const int n   = blockIdx.x >> 6;   // / CIN
    const int ic  = blockIdx.x & 63;   // % CIN

    // Zero never-written halo entries: phys 0..3 and 2052..2055 of each array.
    // No barrier needed before stage-A writes (disjoint: those cover 4..2051);
    // the single barrier below orders both against stage-C reads.
    if (tid < 8) {
        const int j = (tid < 4) ? tid : (2048 + tid);
        s0L[j] = 0.f; s0H[j] = 0.f;
        s1L[j] = 0.f; s1H[j] = 0.f;
    }

    // --- Direct global->register halo load (no LDS staging, no barrier) ---
    const float4* xq = (const float4*)(x + (size_t)(n * CIN + ic) * LEN);
    const float4 z4 = make_float4(0.f, 0.f, 0.f, 0.f);
    const float4 q0 = (tid > 0)      ? xq[2 * tid - 1] : z4;  // x[8t-4..8t-1]
    const float4 q1 = xq[2 * tid];                            // x[8t  ..8t+3]
    const float4 q2 = xq[2 * tid + 1];                        // x[8t+4..8t+7]
    const float4 q3 = (tid < NT - 1) ? xq[2 * tid + 2] : z4;  // x[8t+8..8t+11]

    // E[j] = xe[4t+j-2], O[j] = xo[4t+j-2]   (identical to previous layout)
    float E[8], O[8];
    E[0] = q0.x; O[0] = q0.y; E[1] = q0.z; O[1] = q0.w;
    E[2] = q1.x; O[2] = q1.y; E[3] = q1.z; O[3] = q1.w;
    E[4] = q2.x; O[4] = q2.y; E[5] = q2.z; O[5] = q2.w;
    E[6] = q3.x; O[6] = q3.y; E[7] = q3.z; O[7] = q3.w;
    // For tau = 4*tid+s:  xe[tau-1+i] = E[1+s+i],  xo[tau-2+i] = O[s+i].

    const int oc0 = 2 * ic;

    // --- Stage A+B, BOTH channels in one pass: conv7+bn+gelu+leaky -> Haar ---
    // Weights/BN params are wave-uniform -> SGPRs; doubling channels costs
    // scalar regs + ILP, not VGPRs.
    float wc0[7], wc1[7];
    #pragma unroll
    for (int k = 0; k < 7; ++k) {
        wc0[k] = w1[oc0 * 7 + k];
        wc1[k] = w1[oc0 * 7 + 7 + k];
    }
    const float inv0 = g1[oc0] * rsqrtf(v1[oc0] + 1e-5f);
    const float sh0  = b1[oc0] - m1[oc0] * inv0;
    const float inv1 = g1[oc0 + 1] * rsqrtf(v1[oc0 + 1] + 1e-5f);
    const float sh1  = b1[oc0 + 1] - m1[oc0 + 1] * inv1;

    float Lw0[4], Hw0[4], Lw1[4], Hw1[4];
    #pragma unroll
    for (int s = 0; s < 4; ++s) {
        // h[2*tau]:  xo[t-2]w0 xe[t-1]w1 xo[t-1]w2 xe[t]w3 xo[t]w4 xe[t+1]w5 xo[t+1]w6
        float he0 = O[s] * wc0[0];
        he0 = fmaf(E[1 + s], wc0[1], he0);
        he0 = fmaf(O[s + 1], wc0[2], he0);
        he0 = fmaf(E[2 + s], wc0[3], he0);
        he0 = fmaf(O[s + 2], wc0[4], he0);
        he0 = fmaf(E[3 + s], wc0[5], he0);
        he0 = fmaf(O[s + 3], wc0[6], he0);
        // h[2*tau+1]: xe[t-1]w0 xo[t-1]w1 xe[t]w2 xo[t]w3 xe[t+1]w4 xo[t+1]w5 xe[t+2]w6
        float ho0 = E[1 + s] * wc0[0];
        ho0 = fmaf(O[s + 1], wc0[1], ho0);
        ho0 = fmaf(E[2 + s], wc0[2], ho0);
        ho0 = fmaf(O[s + 2], wc0[3], ho0);
        ho0 = fmaf(E[3 + s], wc0[4], ho0);
        ho0 = fmaf(O[s + 3], wc0[5], ho0);
        ho0 = fmaf(E[4 + s], wc0[6], ho0);

        float he1 = O[s] * wc1[0];
        he1 = fmaf(E[1 + s], wc1[1], he1);
        he1 = fmaf(O[s + 1], wc1[2], he1);
        he1 = fmaf(E[2 + s], wc1[3], he1);
        he1 = fmaf(O[s + 2], wc1[4], he1);
        he1 = fmaf(E[3 + s], wc1[5], he1);
        he1 = fmaf(O[s + 3], wc1[6], he1);
        float ho1 = E[1 + s] * wc1[0];
        ho1 = fmaf(O[s + 1], wc1[1], ho1);
        ho1 = fmaf(E[2 + s], wc1[2], ho1);
        ho1 = fmaf(O[s + 2], wc1[3], ho1);
        ho1 = fmaf(E[3 + s], wc1[4], ho1);
        ho1 = fmaf(O[s + 3], wc1[5], ho1);
        ho1 = fmaf(E[4 + s], wc1[6], ho1);

        float ge0 = gelu_fast(fmaf(he0, inv0, sh0));
        float go0 = gelu_fast(fmaf(ho0, inv0, sh0));
        float ge1 = gelu_fast(fmaf(he1, inv1, sh1));
        float go1 = gelu_fast(fmaf(ho1, inv1, sh1));
        ge0 = fmaxf(ge0, 0.01f * ge0);
        go0 = fmaxf(go0, 0.01f * go0);
        ge1 = fmaxf(ge1, 0.01f * ge1);
        go1 = fmaxf(go1, 0.01f * go1);

        Lw0[s] = (ge0 + go0) * INV_SQRT2;
        Hw0[s] = (ge0 - go0) * INV_SQRT2;
        Lw1[s] = (ge1 + go1) * INV_SQRT2;
        Hw1[s] = (ge1 - go1) * INV_SQRT2;
    }
    ((float4*)s0L)[tid + 1] = make_float4(Lw0[0], Lw0[1], Lw0[2], Lw0[3]);
    ((float4*)s0H)[tid + 1] = make_float4(Hw0[0], Hw0[1], Hw0[2], Hw0[3]);
    ((float4*)s1L)[tid + 1] = make_float4(Lw1[0], Lw1[1], Lw1[2], Lw1[3]);
    ((float4*)s1H)[tid + 1] = make_float4(Hw1[0], Hw1[1], Hw1[2], Hw1[3]);

    __syncthreads();   // the ONLY barrier in the kernel

    // --- Stage C: conv7(xL0)+conv3(xH0) -> inverse Haar + skip + leaky ---
    #pragma unroll
    for (int c = 0; c < 2; ++c) {
        const int oc = oc0 + c;
        const float4* SL4 = (const float4*)(c ? s1L : s0L);
        const float4* SH4 = (const float4*)(c ? s1H : s0H);

        float wl[7], wh[3];
        #pragma unroll
        for (int k = 0; k < 7; ++k) wl[k] = w2L[oc * 7 + k];
        #pragma unroll
        for (int k = 0; k < 3; ++k) wh[k] = w2H[oc * 3 + k];
        const float ws = wskip[oc];

        // Lb[i] = sL[4*tid+i], Hb[i] = sH[4*tid+i], i=0..11 (3 aligned b128 each).
        float Lb[12], Hb[12];
        {
            const float4 p0 = SL4[tid], p1 = SL4[tid + 1], p2 = SL4[tid + 2];
            const float4 r0 = SH4[tid], r1 = SH4[tid + 1], r2 = SH4[tid + 2];
            Lb[0]=p0.x; Lb[1]=p0.y; Lb[2]=p0.z; Lb[3]=p0.w;
            Lb[4]=p1.x; Lb[5]=p1.y; Lb[6]=p1.z; Lb[7]=p1.w;
            Lb[8]=p2.x; Lb[9]=p2.y; Lb[10]=p2.z; Lb[11]=p2.w;
            Hb[0]=r0.x; Hb[1]=r0.y; Hb[2]=r0.z; Hb[3]=r0.w;
            Hb[4]=r1.x; Hb[5]=r1.y; Hb[6]=r1.z; Hb[7]=r1.w;
            Hb[8]=r2.x; Hb[9]=r2.y; Hb[10]=r2.z; Hb[11]=r2.w;
        }
        // xL0[t0-3+i] = Lb[1+i], xH0[t0-3+i] = Hb[1+i]  (t0 = 4*tid)

        float res[8];
        #pragma unroll
        for (int s = 0; s < 4; ++s) {
            // xl = sum_k xL0[t-3+k]*wl[k] = sum_k Lb[1+s+k]*wl[k]
            float xl = Lb[1 + s] * wl[0];
            xl = fmaf(Lb[2 + s], wl[1], xl);
            xl = fmaf(Lb[3 + s], wl[2], xl);
            xl = fmaf(Lb[4 + s], wl[3], xl);
            xl = fmaf(Lb[5 + s], wl[4], xl);
            xl = fmaf(Lb[6 + s], wl[5], xl);
            xl = fmaf(Lb[7 + s], wl[6], xl);
            // xh = sum_k xH0[t-1+k]*wh[k] = sum_k Hb[3+s+k]*wh[k]
            float xh = Hb[3 + s] * wh[0];
            xh = fmaf(Hb[4 + s], wh[1], xh);
            xh = fmaf(Hb[5 + s], wh[2], xh);

            const float re = (xl + xh) * INV_SQRT2;
            const float ro = (xl - xh) * INV_SQRT2;

            // skip: x[2t] = xe[t0+s] = E[2+s], x[2t+1] = xo[t0+s] = O[2+s]
            float oe = fmaf(E[2 + s], ws, re);
            float oo = fmaf(O[2 + s], ws, ro);
            oe = fmaxf(oe, 0.01f * oe);
            oo = fmaxf(oo, 0.01f * oo);
            res[2 * s]     = oe;
            res[2 * s + 1] = oo;
        }

        float4* orow4 = (float4*)(out + (size_t)(n * COUT + oc) * LEN);
        orow4[2 * tid]     = make_float4(res[0], res[1], res[2], res[3]);
        orow4[2 * tid + 1] = make_float4(res[4], res[5], res[6], res[7]);
    }
}

} // namespace

extern "C" void kernel_launch(void* const* d_in, const int* in_sizes, int n_in,
                              void* d_out, int out_size, void* d_ws, size_t ws_size,
                              hipStream_t stream) {
    const float* x    = (const float*)d_in[0];
    const float* w1   = (const float*)d_in[1];
    const float* g1   = (const float*)d_in[2];
    const float* b1   = (const float*)d_in[3];
    const float* m1   = (const float*)d_in[4];
    const float* v1   = (const float*)d_in[5];
    const float* w2L  = (const float*)d_in[6];
    const float* w2H  = (const float*)d_in[7];
    const float* wsk  = (const float*)d_in[8];
    float* out = (float*)d_out;

    const int Bn = in_sizes[0] / (CIN * LEN);   // batch = 64
    fused_wavelet_kernel<<<dim3(Bn * CIN), dim3(NT), 0, stream>>>(
        x, w1, g1, b1, m1, v1, w2L, w2H, wsk, out);
}